// Round 22
// baseline (66.461 us; speedup 1.0000x reference)
//
#include <hip/hip_runtime.h>

// Problem constants
#define NB      20000
#define BATCH   4
#define KNN     16
#define DD      128
#define MW      136
#define BMF     64
#define NSLOTF  157

// persistent-kernel geometry
#define PT_ROWS   32
#define PT_TILES  625                 // 20000/32 exact
#define GB_BYTES  65536               // 512 neighbor-rows x 128 B fp8
#define XB_BYTES  16384               // 32 rows x 512 B f32
#define MB_BYTES  8192                // 32 rows x 256 B bf16 (mean -> upd)
#define HB_BYTES  8192
#define PT_LDS    (GB_BYTES + 2*XB_BYTES + MB_BYTES + HB_BYTES)  // 114688

#if defined(__has_builtin)
#if __has_builtin(__builtin_amdgcn_cvt_pk_f32_fp8)
#define FP8_DEC_BUILTIN 1
#endif
#endif

typedef __attribute__((ext_vector_type(8))) short          bf16x8;
typedef __attribute__((ext_vector_type(4))) float          f32x4;
typedef __attribute__((ext_vector_type(2))) float          f32x2;
typedef __attribute__((ext_vector_type(4))) int            i32x4;
typedef __attribute__((ext_vector_type(2))) int            i32x2;
typedef __attribute__((ext_vector_type(4))) unsigned short u16x4;
typedef __attribute__((ext_vector_type(8))) unsigned short u16x8;

__device__ __forceinline__ unsigned short f2bf(float f) {
    unsigned int u = __float_as_uint(f);
    u += 0x7fffu + ((u >> 16) & 1u);
    return (unsigned short)(u >> 16);
}
__device__ __forceinline__ float bf2f(unsigned short u) {
    return __uint_as_float((unsigned int)u << 16);
}
__device__ __forceinline__ float gelu_fast(float z) {   // tanh-GELU, |err|~1e-4
    float u = z * (0.7978845608028654f + 0.0356774081f * z * z);
    float e = __expf(-2.0f * u);
    return z * __builtin_amdgcn_rcpf(1.0f + e);
}
__device__ __forceinline__ void glds16(const void* g, void* l) {
    __builtin_amdgcn_global_load_lds(
        (const __attribute__((address_space(1))) void*)g,
        (__attribute__((address_space(3))) void*)l, 16, 0, 0);
}
// mid-tile barrier: drain LDS ops only — glds/global loads stay in flight
__device__ __forceinline__ void bar_lgkm() {
    asm volatile("s_waitcnt lgkmcnt(0)" ::: "memory");
    __builtin_amdgcn_sched_barrier(0);
    __builtin_amdgcn_s_barrier();
}
// end-of-tile barrier: full drain
__device__ __forceinline__ void bar_full() {
    asm volatile("s_waitcnt vmcnt(0) lgkmcnt(0)" ::: "memory");
    __builtin_amdgcn_sched_barrier(0);
    __builtin_amdgcn_s_barrier();
}
__device__ __forceinline__ unsigned int f32_to_e4m3(float x) {
    unsigned int u   = __float_as_uint(x);
    unsigned int sgn = (u >> 24) & 0x80u;
    float ax = fabsf(x);
    unsigned int em;
    if (ax < 0.015625f) {
        em = (unsigned int)rintf(ax * 512.0f);
    } else {
        unsigned int mag = __float_as_uint(fminf(ax, 448.0f));
        em = ((mag + 0x7FFFFu + ((mag >> 20) & 1u)) >> 20) - 0x3C0u;
    }
    return sgn | em;
}
__device__ __forceinline__ void acc4_fp8(unsigned int w, float* s) {
#if defined(FP8_DEC_BUILTIN)
    f32x2 lo = __builtin_amdgcn_cvt_pk_f32_fp8((int)w, false);
    f32x2 hi = __builtin_amdgcn_cvt_pk_f32_fp8((int)w, true);
    s[0] += lo[0]; s[1] += lo[1]; s[2] += hi[0]; s[3] += hi[1];
#else
    #pragma unroll
    for (int j = 0; j < 4; ++j) {
        unsigned int b  = (w >> (8 * j)) & 0xFFu;
        unsigned int em = b & 0x7Fu;
        float f  = __uint_as_float((em << 20) + 0x3C000000u);
        float fd = (float)em * 0.001953125f;
        f = (em < 8u) ? fd : f;
        f = __uint_as_float(__float_as_uint(f) | ((b & 0x80u) << 24));
        s[j] += f;
    }
#endif
}

// swizzled weight fragment address (byte ko within a col's 256 B row)
__device__ __forceinline__ const bf16x8* wfrag(const void* W, int col, int ko) {
    return (const bf16x8*)((const char*)W + col * 256 + (ko ^ ((col & 7) << 4)));
}

// ---- fused prep: emb -> fp8 table (blocks 0..4999, only if DO_EMB);
// W1a/W1b/W2 -> bf16 swizzled [col][256B, byte^=(col&7)<<4].
template<bool DO_EMB>
__global__ __launch_bounds__(256) void nr_prep(
    const float* __restrict__ emb, const float* __restrict__ W1,
    const float* __restrict__ W2,
    unsigned char* __restrict__ embq, unsigned short* __restrict__ Wsw)
{
    int bid = blockIdx.x;
    if (DO_EMB && bid < 5000) {
        long long i = ((long long)bid * 256 + threadIdx.x) * 8;
        const float4* p = (const float4*)(emb + i);
        float4 a = p[0], b = p[1];
        unsigned int w0 = f32_to_e4m3(a.x) | (f32_to_e4m3(a.y) << 8) |
                          (f32_to_e4m3(a.z) << 16) | (f32_to_e4m3(a.w) << 24);
        unsigned int w1 = f32_to_e4m3(b.x) | (f32_to_e4m3(b.y) << 8) |
                          (f32_to_e4m3(b.z) << 16) | (f32_to_e4m3(b.w) << 24);
        i32x2 q; q[0] = (int)w0; q[1] = (int)w1;
        *(i32x2*)(embq + i) = q;
    } else {
        int tid = (bid - (DO_EMB ? 5000 : 0)) * 256 + threadIdx.x;   // < 49152
        int w   = tid >> 14;
        int r2  = tid & 16383;
        int col = r2 >> 7;
        int k   = r2 & 127;
        float v;
        if (w == 0)      v = W1[k * DD + col] + W1[(256 + k) * DD + col];
        else if (w == 1) v = W1[(128 + k) * DD + col] - W1[(256 + k) * DD + col];
        else             v = W2[k * DD + col];
        char* dst = (char*)Wsw + w * 32768 + col * 256 + ((k * 2) ^ ((col & 7) << 4));
        *(unsigned short*)dst = f2bf(v);
    }
}

// ---- persistent fused gather+MLP. Per tile: decode prev-staged neighbors ->
// mean; issue next tile's gather+x glds; GEMM1 -> GELU -> GEMM2; upd -> MB;
// flat coalesced epilogue (1 KB per wave store). Weights in registers.
__global__ __launch_bounds__(512, 2) void nr_persist(
    const float* __restrict__ emb, const unsigned char* __restrict__ embq,
    const int* __restrict__ knn, const unsigned short* __restrict__ Wsw,
    const float* __restrict__ b1, const float* __restrict__ b2,
    float* __restrict__ out)
{
    extern __shared__ char L[];
    char* GB  = L;                        // gather stage: [512 nbr][128 B] fp8
    char* XB0 = L + GB_BYTES;             // x f32 dbuf
    char* MB  = XB0 + 2 * XB_BYTES;       // mean bf16 -> upd bf16 (swizzled)
    char* HB  = MB + MB_BYTES;            // h bf16 (swizzled)

    const int t     = threadIdx.x;
    const int xcd   = blockIdx.x & 7;
    const int bslot = blockIdx.x >> 3;    // 0..31
    const int batch = xcd >> 1;
    const int pair  = (xcd & 1) * 32 + bslot;   // 0..63
    const int wv    = t >> 6;
    const int ln    = t & 63;
    const int lrow  = ln & 15;
    const int lk    = ln >> 4;
    const int r     = wv & 1;
    const int cf0   = wv >> 1;
    const int arow  = r * 16 + lrow;
    const int xsw   = (arow & 7) << 4;

    int   colj[2]; float b1v[2], b2v[2];
    #pragma unroll
    for (int j = 0; j < 2; ++j) {
        colj[j] = (cf0 + j * 4) * 16 + lrow;
        b1v[j]  = b1[colj[j]];
        b2v[j]  = b2[colj[j]];
    }

    // weights -> registers (24 x 16 B from L2-hot Wsw; static indices only)
    bf16x8 wA[4][2], wB[4][2], wC[4][2];
    #pragma unroll
    for (int ks = 0; ks < 4; ++ks)
        #pragma unroll
        for (int j = 0; j < 2; ++j) {
            int ko = ks * 64 + lk * 16;
            wA[ks][j] = *wfrag(Wsw, colj[j], ko);
            wB[ks][j] = *wfrag((const char*)Wsw + 32768, colj[j], ko);
            wC[ks][j] = *wfrag((const char*)Wsw + 65536, colj[j], ko);
        }

    const long long brow = (long long)batch * NB;
    const unsigned char* qb = embq + brow * DD;    // batch's fp8 table (L2-hot)
    const int nt = (PT_TILES - pair + 63) >> 6;    // 9 or 10

    auto load_idx = [&](int n, int* iv) {
        const long long r0 = brow + (long long)(pair + n * 64) * PT_ROWS;
        const int* kp = knn + r0 * KNN + wv * 64 + (ln >> 3);
        #pragma unroll
        for (int c = 0; c < 8; ++c) iv[c] = kp[c * 8];
    };
    auto stage_g = [&](const int* iv) {   // 8 async glds -> GB (linear)
        #pragma unroll
        for (int c = 0; c < 8; ++c)
            glds16(qb + (long long)iv[c] * 128 + (ln & 7) * 16,
                   GB + (wv * 8 + c) * 1024);
    };
    auto stage_x = [&](int n) {           // 2 async glds -> XB (pre-swz src)
        const long long r0 = brow + (long long)(pair + n * 64) * PT_ROWS;
        char* xb = XB0 + (n & 1) * XB_BYTES;
        const char* gx = (const char*)emb + r0 * 512;
        #pragma unroll
        for (int ci = 0; ci < 2; ++ci) {
            int ch  = wv * 2 + ci;
            int row = ch * 2 + (ln >> 5);
            int cb  = (ln & 31) * 16;
            glds16(gx + (long long)row * 512 + (cb ^ ((row & 7) << 4)),
                   xb + ch * 1024);
        }
    };
    auto decode_mean = [&]() {            // GB -> mean bf16 -> MB (swizzled)
        int row = t >> 4;
        int e0  = (t & 15) * 8;           // 8 fp8 elems
        float sm[8];
        #pragma unroll
        for (int e = 0; e < 8; ++e) sm[e] = 0.f;
        const char* gbase = GB + row * 2048 + e0;
        #pragma unroll
        for (int k = 0; k < KNN; ++k) {
            i32x2 v = *(const i32x2*)(gbase + k * 128);
            acc4_fp8((unsigned int)v[0], sm + 0);
            acc4_fp8((unsigned int)v[1], sm + 4);
        }
        u16x8 o;
        #pragma unroll
        for (int e = 0; e < 8; ++e) o[e] = f2bf(sm[e] * 0.0625f);
        *(u16x8*)(MB + row * 256 + ((e0 * 2) ^ ((row & 7) << 4))) = o;
    };

    // prologue: tile 0 gather+x; prefetch tile-1 indices
    int ivA[8], ivB[8];
    load_idx(0, ivA);
    stage_g(ivA);
    stage_x(0);
    if (nt > 1) load_idx(1, ivB);
    bar_full();

    for (int n = 0; n < nt; ++n) {
        const int p = n & 1;
        char* xb = XB0 + p * XB_BYTES;
        const long long r0 = brow + (long long)(pair + n * 64) * PT_ROWS;
        const bool have_next = (n + 1 < nt);

        // 1) decode staged neighbors -> MB
        decode_mean();
        bar_lgkm();                        // MB visible, GB free (no vmcnt drain)

        // 2) issue next tile's loads EARLY (hide under GEMMs)
        if (have_next) {
            stage_g(ivB);
            stage_x(n + 1);
            if (n + 2 < nt) load_idx(n + 2, ivA);
        }

        // 3) fragments: x from XB (f32->bf16), mean from MB
        bf16x8 xf[4], mf[4];
        #pragma unroll
        for (int ks = 0; ks < 4; ++ks) {
            int cb = ks * 128 + lk * 32;
            f32x4 a0 = *(const f32x4*)(xb + arow * 512 + ((cb)      ^ xsw));
            f32x4 a1 = *(const f32x4*)(xb + arow * 512 + ((cb + 16) ^ xsw));
            u16x8 xt;
            xt[0]=f2bf(a0[0]); xt[1]=f2bf(a0[1]); xt[2]=f2bf(a0[2]); xt[3]=f2bf(a0[3]);
            xt[4]=f2bf(a1[0]); xt[5]=f2bf(a1[1]); xt[6]=f2bf(a1[2]); xt[7]=f2bf(a1[3]);
            xf[ks] = *(bf16x8*)&xt;
            mf[ks] = *(const bf16x8*)(MB + arow * 256 + ((ks * 64 + lk * 16) ^ xsw));
        }

        // 4) GEMM1 (register weights)
        f32x4 acc[2];
        acc[0] = (f32x4){0.f,0.f,0.f,0.f}; acc[1] = (f32x4){0.f,0.f,0.f,0.f};
        #pragma unroll
        for (int ks = 0; ks < 4; ++ks)
            #pragma unroll
            for (int j = 0; j < 2; ++j)
                acc[j] = __builtin_amdgcn_mfma_f32_16x16x32_bf16(xf[ks], wA[ks][j], acc[j], 0, 0, 0);
        #pragma unroll
        for (int ks = 0; ks < 4; ++ks)
            #pragma unroll
            for (int j = 0; j < 2; ++j)
                acc[j] = __builtin_amdgcn_mfma_f32_16x16x32_bf16(mf[ks], wB[ks][j], acc[j], 0, 0, 0);

        // 5) h -> HB (bf16, swizzled)
        #pragma unroll
        for (int j = 0; j < 2; ++j)
            #pragma unroll
            for (int rr = 0; rr < 4; ++rr) {
                int row = r * 16 + lk * 4 + rr;
                *(unsigned short*)(HB + row * 256 + ((colj[j] * 2) ^ ((row & 7) << 4)))
                    = f2bf(gelu_fast(acc[j][rr] + b1v[j]));
            }
        bar_lgkm();                        // h visible; ALL waves' mean reads done

        // 6) GEMM2
        bf16x8 hf[4];
        #pragma unroll
        for (int ks = 0; ks < 4; ++ks)
            hf[ks] = *(const bf16x8*)(HB + arow * 256 + ((ks * 64 + lk * 16) ^ xsw));
        f32x4 acc2[2];
        acc2[0] = (f32x4){0.f,0.f,0.f,0.f}; acc2[1] = (f32x4){0.f,0.f,0.f,0.f};
        #pragma unroll
        for (int ks = 0; ks < 4; ++ks)
            #pragma unroll
            for (int j = 0; j < 2; ++j)
                acc2[j] = __builtin_amdgcn_mfma_f32_16x16x32_bf16(hf[ks], wC[ks][j], acc2[j], 0, 0, 0);

        // 7) upd -> MB (bf16, swizzled). Safe: mean reads finished before the
        //    h-barrier; next-tile decode writes MB only after bar_full.
        #pragma unroll
        for (int j = 0; j < 2; ++j)
            #pragma unroll
            for (int rr = 0; rr < 4; ++rr) {
                int row = r * 16 + lk * 4 + rr;
                *(unsigned short*)(MB + row * 256 + ((colj[j] * 2) ^ ((row & 7) << 4)))
                    = f2bf(acc2[j][rr] + b2v[j]);
            }
        bar_lgkm();                        // upd visible; glds stay in flight

        // 8) flat coalesced epilogue: each wave store covers 1 KB contiguous
        #pragma unroll
        for (int i = 0; i < 2; ++i) {
            int flat = i * 2048 + t * 4;   // f32 index in 32x128 tile
            int row  = flat >> 7;
            int col  = flat & 127;
            int sw   = (row & 7) << 4;
            u16x4 uv = *(const u16x4*)(MB + row * 256 + ((col * 2) ^ sw));
            f32x4 rv = *(const f32x4*)(xb + row * 512 + ((col * 4) ^ sw));
            f32x4 ov;
            ov[0] = rv[0] + bf2f(uv[0]); ov[1] = rv[1] + bf2f(uv[1]);
            ov[2] = rv[2] + bf2f(uv[2]); ov[3] = rv[3] + bf2f(uv[3]);
            *(f32x4*)(out + r0 * 128 + flat) = ov;
        }

        // 9) rotate prefetched indices, tile handoff
        if (have_next) {
            #pragma unroll
            for (int c = 0; c < 8; ++c) ivB[c] = ivA[c];
        }
        bar_full();
    }
}

// ---- deep fallback (ws < 10.3 MB): f32 in-kernel gather, one fused pass
__global__ __launch_bounds__(256, 3) void nr_fused_f32(
    const float* __restrict__ emb, const int* __restrict__ knn,
    const unsigned short* __restrict__ Wsw,
    const float* __restrict__ b1, const float* __restrict__ b2,
    float* __restrict__ out)
{
    extern __shared__ char ldsraw[];
    float*          ldsxF = (float*)ldsraw;
    unsigned short* ldsm  = (unsigned short*)(ldsraw + BMF * DD * 4);

    const int t     = threadIdx.x;
    const int xcd   = blockIdx.x & 7;
    const int slot  = blockIdx.x >> 3;
    const int batch = xcd >> 1;
    const int bib   = (xcd & 1) * NSLOTF + slot;
    const int mend  = batch * NB + NB;
    int m_base = batch * NB + bib * BMF;
    if (m_base + BMF > mend) m_base = mend - BMF;

    {
        const int node_local = t >> 2;
        const int dpart      = t & 3;
        const int m  = m_base + node_local;

        const f32x4* xp = (const f32x4*)(emb + (long long)m * DD + dpart * 32);
        float* xrow = ldsxF + node_local * DD + dpart * 32;
        #pragma unroll
        for (int j = 0; j < 8; ++j) {
            f32x4 v = xp[j];
            *(f32x4*)(xrow + j*4) = v;
        }
        int idx[KNN];
        const i32x4* kp4 = (const i32x4*)(knn + (long long)m * KNN);
        #pragma unroll
        for (int q = 0; q < 4; ++q) {
            i32x4 v = __builtin_nontemporal_load(kp4 + q);
            idx[4*q+0]=v[0]; idx[4*q+1]=v[1]; idx[4*q+2]=v[2]; idx[4*q+3]=v[3];
        }
        float sm[32];
        #pragma unroll
        for (int e = 0; e < 32; ++e) sm[e] = 0.f;
        const long long bbase = (long long)batch * NB * DD + dpart * 32;
        #pragma unroll 4
        for (int k = 0; k < KNN; ++k) {
            const f32x4* np = (const f32x4*)(emb + bbase + (long long)idx[k] * DD);
            #pragma unroll
            for (int j = 0; j < 8; ++j) {
                f32x4 v = np[j];
                sm[j*4+0]+=v[0]; sm[j*4+1]+=v[1]; sm[j*4+2]+=v[2]; sm[j*4+3]+=v[3];
            }
        }
        unsigned short* mrow = ldsm + node_local * MW + dpart * 32;
        #pragma unroll
        for (int j = 0; j < 8; ++j) {
            u16x4 pm;
            #pragma unroll
            for (int e = 0; e < 4; ++e) pm[e] = f2bf(sm[j*4+e] * 0.0625f);
            *(u16x4*)(mrow + j*4) = pm;
        }
    }
    __syncthreads();

    const int wave = t >> 6;
    const int lane = t & 63;
    const int lrow = lane & 15;
    const int lk   = lane >> 4;
    const int Arow = wave * 16 + lrow;

    bf16x8 xf[4], mf[4];
    {
        const float* xr = ldsxF + Arow * DD + lk * 8;
        const unsigned short* mr = ldsm + Arow * MW + lk * 8;
        #pragma unroll
        for (int ks = 0; ks < 4; ++ks) {
            f32x4 a0 = *(const f32x4*)(xr + ks * 32);
            f32x4 a1 = *(const f32x4*)(xr + ks * 32 + 4);
            u16x8 xt;
            xt[0]=f2bf(a0[0]); xt[1]=f2bf(a0[1]); xt[2]=f2bf(a0[2]); xt[3]=f2bf(a0[3]);
            xt[4]=f2bf(a1[0]); xt[5]=f2bf(a1[1]); xt[6]=f2bf(a1[2]); xt[7]=f2bf(a1[3]);
            xf[ks] = *(bf16x8*)&xt;
            mf[ks] = *(const bf16x8*)(mr + ks * 32);
        }
    }

    f32x4 acc[8];
    #pragma unroll
    for (int f = 0; f < 8; ++f) acc[f] = (f32x4){0.f, 0.f, 0.f, 0.f};
    #pragma unroll
    for (int ks = 0; ks < 4; ++ks)
        #pragma unroll
        for (int f = 0; f < 8; ++f) {
            bf16x8 bw = *wfrag(Wsw, f * 16 + lrow, ks * 64 + lk * 16);
            acc[f] = __builtin_amdgcn_mfma_f32_16x16x32_bf16(xf[ks], bw, acc[f], 0, 0, 0);
        }
    #pragma unroll
    for (int ks = 0; ks < 4; ++ks)
        #pragma unroll
        for (int f = 0; f < 8; ++f) {
            bf16x8 bw = *wfrag((const char*)Wsw + 32768, f * 16 + lrow, ks * 64 + lk * 16);
            acc[f] = __builtin_amdgcn_mfma_f32_16x16x32_bf16(mf[ks], bw, acc[f], 0, 0, 0);
        }
    __syncthreads();

    #pragma unroll
    for (int f = 0; f < 8; ++f) {
        int col = f * 16 + lrow;
        float bb = b1[col];
        #pragma unroll
        for (int rr = 0; rr < 4; ++rr) {
            int row = wave * 16 + lk * 4 + rr;
            ldsm[row * MW + col] = f2bf(gelu_fast(acc[f][rr] + bb));
        }
    }
    __syncthreads();

    f32x4 acc2[8];
    #pragma unroll
    for (int f = 0; f < 8; ++f) acc2[f] = (f32x4){0.f, 0.f, 0.f, 0.f};
    {
        const unsigned short* abase = ldsm + Arow * MW + lk * 8;
        #pragma unroll
        for (int ks = 0; ks < 4; ++ks) {
            bf16x8 af = *(const bf16x8*)(abase + ks * 32);
            #pragma unroll
            for (int f = 0; f < 8; ++f) {
                bf16x8 bw = *wfrag((const char*)Wsw + 65536, f * 16 + lrow, ks * 64 + lk * 16);
                acc2[f] = __builtin_amdgcn_mfma_f32_16x16x32_bf16(af, bw, acc2[f], 0, 0, 0);
            }
        }
    }

    #pragma unroll
    for (int f = 0; f < 8; ++f) {
        int col = f * 16 + lrow;
        float bb = b2[col];
        #pragma unroll
        for (int rr = 0; rr < 4; ++rr) {
            int row = wave * 16 + lk * 4 + rr;
            float xv = ldsxF[row * DD + col];
            out[(long long)(m_base + row) * DD + col] = acc2[f][rr] + bb + xv;
        }
    }
}

extern "C" void kernel_launch(void* const* d_in, const int* in_sizes, int n_in,
                              void* d_out, int out_size, void* d_ws, size_t ws_size,
                              hipStream_t stream) {
    const float* emb = (const float*)d_in[0];
    const int*   knn = (const int*)  d_in[1];
    const float* W1  = (const float*)d_in[2];
    const float* b1  = (const float*)d_in[3];
    const float* W2  = (const float*)d_in[4];
    const float* b2  = (const float*)d_in[5];
    float* out = (float*)d_out;

    unsigned short* Wsw  = (unsigned short*)d_ws;           // 49152 u16 swizzled
    unsigned char*  embq = (unsigned char*)(Wsw + 49152);   // 10,240,000 fp8

    const size_t NEED   = (size_t)98304 + 10240000;         // ~10.3 MB
    const size_t LDSB_F = (size_t)BMF * DD * 4 + (size_t)BMF * MW * 2;

    if (ws_size >= NEED) {
        hipError_t e = hipFuncSetAttribute(
            reinterpret_cast<const void*>(nr_persist),
            hipFuncAttributeMaxDynamicSharedMemorySize, PT_LDS);
        nr_prep<true><<<5192, 256, 0, stream>>>(emb, W1, W2, embq, Wsw);
        if (e == hipSuccess) {
            nr_persist<<<256, 512, PT_LDS, stream>>>(
                emb, embq, knn, Wsw, b1, b2, out);
            return;
        }
    } else {
        nr_prep<false><<<192, 256, 0, stream>>>(emb, W1, W2, nullptr, Wsw);
    }
    nr_fused_f32<<<8 * NSLOTF, 256, LDSB_F, stream>>>(
        emb, knn, Wsw, b1, b2, out);
}

// Round 23
// 52.511 us; speedup vs baseline: 1.2657x; 1.2657x over previous
//
#include <hip/hip_runtime.h>

// Problem constants
#define NB      20000
#define BATCH   4
#define KNN     16
#define DD      128
#define MW      136
#define BMF     64
#define NSLOTF  157

// persistent-kernel geometry: 16-row tiles, 256-thread blocks, 2 blocks/CU
#define PT_ROWS   16
#define PT_TPB    1250                // tiles per batch (20000/16)
#define GB_BYTES  32768               // 256 neighbor-rows x 128 B fp8
#define XB_BYTES  8192                // 16 rows x 512 B f32
#define MB_BYTES  4096                // 16 rows x 256 B bf16 (mean -> upd)
#define HB_BYTES  4096
#define PT_LDS    (GB_BYTES + 2*XB_BYTES + MB_BYTES + HB_BYTES)  // 57344 < 64K

#if defined(__has_builtin)
#if __has_builtin(__builtin_amdgcn_cvt_pk_f32_fp8)
#define FP8_DEC_BUILTIN 1
#endif
#endif

typedef __attribute__((ext_vector_type(8))) short          bf16x8;
typedef __attribute__((ext_vector_type(4))) float          f32x4;
typedef __attribute__((ext_vector_type(2))) float          f32x2;
typedef __attribute__((ext_vector_type(4))) int            i32x4;
typedef __attribute__((ext_vector_type(2))) int            i32x2;
typedef __attribute__((ext_vector_type(4))) unsigned short u16x4;
typedef __attribute__((ext_vector_type(8))) unsigned short u16x8;

__device__ __forceinline__ unsigned short f2bf(float f) {
    unsigned int u = __float_as_uint(f);
    u += 0x7fffu + ((u >> 16) & 1u);
    return (unsigned short)(u >> 16);
}
__device__ __forceinline__ float bf2f(unsigned short u) {
    return __uint_as_float((unsigned int)u << 16);
}
__device__ __forceinline__ float gelu_fast(float z) {   // tanh-GELU, |err|~1e-4
    float u = z * (0.7978845608028654f + 0.0356774081f * z * z);
    float e = __expf(-2.0f * u);
    return z * __builtin_amdgcn_rcpf(1.0f + e);
}
__device__ __forceinline__ void glds16(const void* g, void* l) {
    __builtin_amdgcn_global_load_lds(
        (const __attribute__((address_space(1))) void*)g,
        (__attribute__((address_space(3))) void*)l, 16, 0, 0);
}
// mid-tile barrier: drain LDS ops only — glds/global loads stay in flight
__device__ __forceinline__ void bar_lgkm() {
    asm volatile("s_waitcnt lgkmcnt(0)" ::: "memory");
    __builtin_amdgcn_sched_barrier(0);
    __builtin_amdgcn_s_barrier();
}
// end-of-tile barrier: full drain
__device__ __forceinline__ void bar_full() {
    asm volatile("s_waitcnt vmcnt(0) lgkmcnt(0)" ::: "memory");
    __builtin_amdgcn_sched_barrier(0);
    __builtin_amdgcn_s_barrier();
}
__device__ __forceinline__ unsigned int f32_to_e4m3(float x) {
    unsigned int u   = __float_as_uint(x);
    unsigned int sgn = (u >> 24) & 0x80u;
    float ax = fabsf(x);
    unsigned int em;
    if (ax < 0.015625f) {
        em = (unsigned int)rintf(ax * 512.0f);
    } else {
        unsigned int mag = __float_as_uint(fminf(ax, 448.0f));
        em = ((mag + 0x7FFFFu + ((mag >> 20) & 1u)) >> 20) - 0x3C0u;
    }
    return sgn | em;
}
__device__ __forceinline__ void acc4_fp8(unsigned int w, float* s) {
#if defined(FP8_DEC_BUILTIN)
    f32x2 lo = __builtin_amdgcn_cvt_pk_f32_fp8((int)w, false);
    f32x2 hi = __builtin_amdgcn_cvt_pk_f32_fp8((int)w, true);
    s[0] += lo[0]; s[1] += lo[1]; s[2] += hi[0]; s[3] += hi[1];
#else
    #pragma unroll
    for (int j = 0; j < 4; ++j) {
        unsigned int b  = (w >> (8 * j)) & 0xFFu;
        unsigned int em = b & 0x7Fu;
        float f  = __uint_as_float((em << 20) + 0x3C000000u);
        float fd = (float)em * 0.001953125f;
        f = (em < 8u) ? fd : f;
        f = __uint_as_float(__float_as_uint(f) | ((b & 0x80u) << 24));
        s[j] += f;
    }
#endif
}

// swizzled weight fragment address (byte ko within a col's 256 B row)
__device__ __forceinline__ const bf16x8* wfrag(const void* W, int col, int ko) {
    return (const bf16x8*)((const char*)W + col * 256 + (ko ^ ((col & 7) << 4)));
}

// ---- fused prep: emb -> fp8 table (blocks 0..4999, only if DO_EMB);
// W1a/W1b/W2 -> bf16 swizzled [col][256B, byte^=(col&7)<<4].
template<bool DO_EMB>
__global__ __launch_bounds__(256) void nr_prep(
    const float* __restrict__ emb, const float* __restrict__ W1,
    const float* __restrict__ W2,
    unsigned char* __restrict__ embq, unsigned short* __restrict__ Wsw)
{
    int bid = blockIdx.x;
    if (DO_EMB && bid < 5000) {
        long long i = ((long long)bid * 256 + threadIdx.x) * 8;
        const float4* p = (const float4*)(emb + i);
        float4 a = p[0], b = p[1];
        unsigned int w0 = f32_to_e4m3(a.x) | (f32_to_e4m3(a.y) << 8) |
                          (f32_to_e4m3(a.z) << 16) | (f32_to_e4m3(a.w) << 24);
        unsigned int w1 = f32_to_e4m3(b.x) | (f32_to_e4m3(b.y) << 8) |
                          (f32_to_e4m3(b.z) << 16) | (f32_to_e4m3(b.w) << 24);
        i32x2 q; q[0] = (int)w0; q[1] = (int)w1;
        *(i32x2*)(embq + i) = q;
    } else {
        int tid = (bid - (DO_EMB ? 5000 : 0)) * 256 + threadIdx.x;   // < 49152
        int w   = tid >> 14;
        int r2  = tid & 16383;
        int col = r2 >> 7;
        int k   = r2 & 127;
        float v;
        if (w == 0)      v = W1[k * DD + col] + W1[(256 + k) * DD + col];
        else if (w == 1) v = W1[(128 + k) * DD + col] - W1[(256 + k) * DD + col];
        else             v = W2[k * DD + col];
        char* dst = (char*)Wsw + w * 32768 + col * 256 + ((k * 2) ^ ((col & 7) << 4));
        *(unsigned short*)dst = f2bf(v);
    }
}

// ---- persistent fused gather+MLP, 16-row tiles, 256 threads, 2 blocks/CU.
// Two independent barrier domains per CU: block A's compute hides block B's
// barrier drains (the R19-R22 plateau was 1 barrier-coupled block/CU).
__global__ __launch_bounds__(256, 2) void nr_persist(
    const float* __restrict__ emb, const unsigned char* __restrict__ embq,
    const int* __restrict__ knn, const unsigned short* __restrict__ Wsw,
    const float* __restrict__ b1, const float* __restrict__ b2,
    float* __restrict__ out)
{
    extern __shared__ char L[];
    char* GB  = L;                        // gather stage: [256 nbr][128 B] fp8
    char* XB0 = L + GB_BYTES;             // x f32 dbuf
    char* MB  = XB0 + 2 * XB_BYTES;       // mean bf16 -> upd bf16 (swizzled)
    char* HB  = MB + MB_BYTES;            // h bf16 (swizzled)

    const int t     = threadIdx.x;
    const int xcd   = blockIdx.x & 7;
    const int bslot = blockIdx.x >> 3;    // 0..63
    const int batch = xcd >> 1;
    const int pair  = (xcd & 1) * 64 + bslot;   // 0..127
    const int wv    = t >> 6;             // 0..3
    const int ln    = t & 63;
    const int lrow  = ln & 15;
    const int lk    = ln >> 4;
    const int arow  = lrow;               // 16 rows, all waves share them
    const int xsw   = (arow & 7) << 4;

    int   colj[2]; float b1v[2], b2v[2];
    #pragma unroll
    for (int j = 0; j < 2; ++j) {
        colj[j] = wv * 32 + j * 16 + lrow;   // wave owns cols [wv*32, wv*32+32)
        b1v[j]  = b1[colj[j]];
        b2v[j]  = b2[colj[j]];
    }

    // weights -> registers (24 x 16 B from L2-hot Wsw; static indices only)
    bf16x8 wA[4][2], wB[4][2], wC[4][2];
    #pragma unroll
    for (int ks = 0; ks < 4; ++ks)
        #pragma unroll
        for (int j = 0; j < 2; ++j) {
            int ko = ks * 64 + lk * 16;
            wA[ks][j] = *wfrag(Wsw, colj[j], ko);
            wB[ks][j] = *wfrag((const char*)Wsw + 32768, colj[j], ko);
            wC[ks][j] = *wfrag((const char*)Wsw + 65536, colj[j], ko);
        }

    const long long brow = (long long)batch * NB;
    const unsigned char* qb = embq + brow * DD;    // batch's fp8 table (L2-hot)
    const int nt = (PT_TPB - pair + 127) >> 7;     // 9 or 10

    auto load_idx = [&](int n, int* iv) {
        // slot s = wv*64 + c*8 + (ln>>3) in [0,256): row s>>4, neighbor s&15
        const long long r0 = brow + (long long)(pair + n * 128) * PT_ROWS;
        const int* kp = knn + r0 * KNN + wv * 64 + (ln >> 3);
        #pragma unroll
        for (int c = 0; c < 8; ++c) iv[c] = kp[c * 8];
    };
    auto stage_g = [&](const int* iv) {   // 8 async glds -> GB (linear)
        #pragma unroll
        for (int c = 0; c < 8; ++c)
            glds16(qb + (long long)iv[c] * 128 + (ln & 7) * 16,
                   GB + (wv * 8 + c) * 1024);
    };
    auto stage_x = [&](int n) {           // 2 async glds -> XB (pre-swz src)
        const long long r0 = brow + (long long)(pair + n * 128) * PT_ROWS;
        char* xb = XB0 + (n & 1) * XB_BYTES;
        const char* gx = (const char*)emb + r0 * 512;
        #pragma unroll
        for (int ci = 0; ci < 2; ++ci) {
            int ch  = wv * 2 + ci;        // 0..7, 1 KB each = 2 rows
            int row = ch * 2 + (ln >> 5);
            int cb  = (ln & 31) * 16;
            glds16(gx + (long long)row * 512 + (cb ^ ((row & 7) << 4)),
                   xb + ch * 1024);
        }
    };
    auto decode_mean = [&]() {            // GB -> mean bf16 -> MB (swizzled)
        int row = t >> 4;                 // 0..15
        int e0  = (t & 15) * 8;           // 8 fp8 elems
        float sm[8];
        #pragma unroll
        for (int e = 0; e < 8; ++e) sm[e] = 0.f;
        const char* gbase = GB + row * 2048 + e0;
        #pragma unroll
        for (int k = 0; k < KNN; ++k) {
            i32x2 v = *(const i32x2*)(gbase + k * 128);
            acc4_fp8((unsigned int)v[0], sm + 0);
            acc4_fp8((unsigned int)v[1], sm + 4);
        }
        u16x8 o;
        #pragma unroll
        for (int e = 0; e < 8; ++e) o[e] = f2bf(sm[e] * 0.0625f);
        *(u16x8*)(MB + row * 256 + ((e0 * 2) ^ ((row & 7) << 4))) = o;
    };

    // prologue: tile 0 gather+x; prefetch tile-1 indices
    int ivA[8], ivB[8];
    load_idx(0, ivA);
    stage_g(ivA);
    stage_x(0);
    if (nt > 1) load_idx(1, ivB);
    bar_full();

    for (int n = 0; n < nt; ++n) {
        const int p = n & 1;
        char* xb = XB0 + p * XB_BYTES;
        const long long r0 = brow + (long long)(pair + n * 128) * PT_ROWS;
        const bool have_next = (n + 1 < nt);

        // 1) decode staged neighbors -> MB
        decode_mean();
        bar_lgkm();                        // MB visible, GB free (no vmcnt drain)

        // 2) issue next tile's loads EARLY (hide under GEMMs)
        if (have_next) {
            stage_g(ivB);
            stage_x(n + 1);
            if (n + 2 < nt) load_idx(n + 2, ivA);
        }

        // 3) fragments: x from XB (f32->bf16), mean from MB
        bf16x8 xf[4], mf[4];
        #pragma unroll
        for (int ks = 0; ks < 4; ++ks) {
            int cb = ks * 128 + lk * 32;
            f32x4 a0 = *(const f32x4*)(xb + arow * 512 + ((cb)      ^ xsw));
            f32x4 a1 = *(const f32x4*)(xb + arow * 512 + ((cb + 16) ^ xsw));
            u16x8 xt;
            xt[0]=f2bf(a0[0]); xt[1]=f2bf(a0[1]); xt[2]=f2bf(a0[2]); xt[3]=f2bf(a0[3]);
            xt[4]=f2bf(a1[0]); xt[5]=f2bf(a1[1]); xt[6]=f2bf(a1[2]); xt[7]=f2bf(a1[3]);
            xf[ks] = *(bf16x8*)&xt;
            mf[ks] = *(const bf16x8*)(MB + arow * 256 + ((ks * 64 + lk * 16) ^ xsw));
        }

        // 4) GEMM1 (register weights)
        f32x4 acc[2];
        acc[0] = (f32x4){0.f,0.f,0.f,0.f}; acc[1] = (f32x4){0.f,0.f,0.f,0.f};
        #pragma unroll
        for (int ks = 0; ks < 4; ++ks)
            #pragma unroll
            for (int j = 0; j < 2; ++j)
                acc[j] = __builtin_amdgcn_mfma_f32_16x16x32_bf16(xf[ks], wA[ks][j], acc[j], 0, 0, 0);
        #pragma unroll
        for (int ks = 0; ks < 4; ++ks)
            #pragma unroll
            for (int j = 0; j < 2; ++j)
                acc[j] = __builtin_amdgcn_mfma_f32_16x16x32_bf16(mf[ks], wB[ks][j], acc[j], 0, 0, 0);

        // 5) h -> HB (bf16, swizzled)
        #pragma unroll
        for (int j = 0; j < 2; ++j)
            #pragma unroll
            for (int rr = 0; rr < 4; ++rr) {
                int row = lk * 4 + rr;
                *(unsigned short*)(HB + row * 256 + ((colj[j] * 2) ^ ((row & 7) << 4)))
                    = f2bf(gelu_fast(acc[j][rr] + b1v[j]));
            }
        bar_lgkm();                        // h visible; mean reads all done

        // 6) GEMM2
        bf16x8 hf[4];
        #pragma unroll
        for (int ks = 0; ks < 4; ++ks)
            hf[ks] = *(const bf16x8*)(HB + arow * 256 + ((ks * 64 + lk * 16) ^ xsw));
        f32x4 acc2[2];
        acc2[0] = (f32x4){0.f,0.f,0.f,0.f}; acc2[1] = (f32x4){0.f,0.f,0.f,0.f};
        #pragma unroll
        for (int ks = 0; ks < 4; ++ks)
            #pragma unroll
            for (int j = 0; j < 2; ++j)
                acc2[j] = __builtin_amdgcn_mfma_f32_16x16x32_bf16(hf[ks], wC[ks][j], acc2[j], 0, 0, 0);

        // 7) upd -> MB (safe: mean reads done before the h-barrier; next-tile
        //    decode writes MB only after bar_full)
        #pragma unroll
        for (int j = 0; j < 2; ++j)
            #pragma unroll
            for (int rr = 0; rr < 4; ++rr) {
                int row = lk * 4 + rr;
                *(unsigned short*)(MB + row * 256 + ((colj[j] * 2) ^ ((row & 7) << 4)))
                    = f2bf(acc2[j][rr] + b2v[j]);
            }
        bar_lgkm();                        // upd visible; glds stay in flight

        // 8) flat coalesced epilogue: each wave store covers 1 KB contiguous
        #pragma unroll
        for (int i = 0; i < 2; ++i) {
            int flat = i * 1024 + t * 4;   // f32 index in 16x128 tile
            int row  = flat >> 7;
            int col  = flat & 127;
            int sw   = (row & 7) << 4;
            u16x4 uv = *(const u16x4*)(MB + row * 256 + ((col * 2) ^ sw));
            f32x4 rv = *(const f32x4*)(xb + row * 512 + ((col * 4) ^ sw));
            f32x4 ov;
            ov[0] = rv[0] + bf2f(uv[0]); ov[1] = rv[1] + bf2f(uv[1]);
            ov[2] = rv[2] + bf2f(uv[2]); ov[3] = rv[3] + bf2f(uv[3]);
            *(f32x4*)(out + r0 * 128 + flat) = ov;
        }

        // 9) rotate prefetched indices, tile handoff
        if (have_next) {
            #pragma unroll
            for (int c = 0; c < 8; ++c) ivB[c] = ivA[c];
        }
        bar_full();
    }
}

// ---- deep fallback (ws < 10.3 MB): f32 in-kernel gather, one fused pass
__global__ __launch_bounds__(256, 3) void nr_fused_f32(
    const float* __restrict__ emb, const int* __restrict__ knn,
    const unsigned short* __restrict__ Wsw,
    const float* __restrict__ b1, const float* __restrict__ b2,
    float* __restrict__ out)
{
    extern __shared__ char ldsraw[];
    float*          ldsxF = (float*)ldsraw;
    unsigned short* ldsm  = (unsigned short*)(ldsraw + BMF * DD * 4);

    const int t     = threadIdx.x;
    const int xcd   = blockIdx.x & 7;
    const int slot  = blockIdx.x >> 3;
    const int batch = xcd >> 1;
    const int bib   = (xcd & 1) * NSLOTF + slot;
    const int mend  = batch * NB + NB;
    int m_base = batch * NB + bib * BMF;
    if (m_base + BMF > mend) m_base = mend - BMF;

    {
        const int node_local = t >> 2;
        const int dpart      = t & 3;
        const int m  = m_base + node_local;

        const f32x4* xp = (const f32x4*)(emb + (long long)m * DD + dpart * 32);
        float* xrow = ldsxF + node_local * DD + dpart * 32;
        #pragma unroll
        for (int j = 0; j < 8; ++j) {
            f32x4 v = xp[j];
            *(f32x4*)(xrow + j*4) = v;
        }
        int idx[KNN];
        const i32x4* kp4 = (const i32x4*)(knn + (long long)m * KNN);
        #pragma unroll
        for (int q = 0; q < 4; ++q) {
            i32x4 v = __builtin_nontemporal_load(kp4 + q);
            idx[4*q+0]=v[0]; idx[4*q+1]=v[1]; idx[4*q+2]=v[2]; idx[4*q+3]=v[3];
        }
        float sm[32];
        #pragma unroll
        for (int e = 0; e < 32; ++e) sm[e] = 0.f;
        const long long bbase = (long long)batch * NB * DD + dpart * 32;
        #pragma unroll 4
        for (int k = 0; k < KNN; ++k) {
            const f32x4* np = (const f32x4*)(emb + bbase + (long long)idx[k] * DD);
            #pragma unroll
            for (int j = 0; j < 8; ++j) {
                f32x4 v = np[j];
                sm[j*4+0]+=v[0]; sm[j*4+1]+=v[1]; sm[j*4+2]+=v[2]; sm[j*4+3]+=v[3];
            }
        }
        unsigned short* mrow = ldsm + node_local * MW + dpart * 32;
        #pragma unroll
        for (int j = 0; j < 8; ++j) {
            u16x4 pm;
            #pragma unroll
            for (int e = 0; e < 4; ++e) pm[e] = f2bf(sm[j*4+e] * 0.0625f);
            *(u16x4*)(mrow + j*4) = pm;
        }
    }
    __syncthreads();

    const int wave = t >> 6;
    const int lane = t & 63;
    const int lrow = lane & 15;
    const int lk   = lane >> 4;
    const int Arow = wave * 16 + lrow;

    bf16x8 xf[4], mf[4];
    {
        const float* xr = ldsxF + Arow * DD + lk * 8;
        const unsigned short* mr = ldsm + Arow * MW + lk * 8;
        #pragma unroll
        for (int ks = 0; ks < 4; ++ks) {
            f32x4 a0 = *(const f32x4*)(xr + ks * 32);
            f32x4 a1 = *(const f32x4*)(xr + ks * 32 + 4);
            u16x8 xt;
            xt[0]=f2bf(a0[0]); xt[1]=f2bf(a0[1]); xt[2]=f2bf(a0[2]); xt[3]=f2bf(a0[3]);
            xt[4]=f2bf(a1[0]); xt[5]=f2bf(a1[1]); xt[6]=f2bf(a1[2]); xt[7]=f2bf(a1[3]);
            xf[ks] = *(bf16x8*)&xt;
            mf[ks] = *(const bf16x8*)(mr + ks * 32);
        }
    }

    f32x4 acc[8];
    #pragma unroll
    for (int f = 0; f < 8; ++f) acc[f] = (f32x4){0.f, 0.f, 0.f, 0.f};
    #pragma unroll
    for (int ks = 0; ks < 4; ++ks)
        #pragma unroll
        for (int f = 0; f < 8; ++f) {
            bf16x8 bw = *wfrag(Wsw, f * 16 + lrow, ks * 64 + lk * 16);
            acc[f] = __builtin_amdgcn_mfma_f32_16x16x32_bf16(xf[ks], bw, acc[f], 0, 0, 0);
        }
    #pragma unroll
    for (int ks = 0; ks < 4; ++ks)
        #pragma unroll
        for (int f = 0; f < 8; ++f) {
            bf16x8 bw = *wfrag((const char*)Wsw + 32768, f * 16 + lrow, ks * 64 + lk * 16);
            acc[f] = __builtin_amdgcn_mfma_f32_16x16x32_bf16(mf[ks], bw, acc[f], 0, 0, 0);
        }
    __syncthreads();

    #pragma unroll
    for (int f = 0; f < 8; ++f) {
        int col = f * 16 + lrow;
        float bb = b1[col];
        #pragma unroll
        for (int rr = 0; rr < 4; ++rr) {
            int row = wave * 16 + lk * 4 + rr;
            ldsm[row * MW + col] = f2bf(gelu_fast(acc[f][rr] + bb));
        }
    }
    __syncthreads();

    f32x4 acc2[8];
    #pragma unroll
    for (int f = 0; f < 8; ++f) acc2[f] = (f32x4){0.f, 0.f, 0.f, 0.f};
    {
        const unsigned short* abase = ldsm + Arow * MW + lk * 8;
        #pragma unroll
        for (int ks = 0; ks < 4; ++ks) {
            bf16x8 af = *(const bf16x8*)(abase + ks * 32);
            #pragma unroll
            for (int f = 0; f < 8; ++f) {
                bf16x8 bw = *wfrag((const char*)Wsw + 65536, f * 16 + lrow, ks * 64 + lk * 16);
                acc2[f] = __builtin_amdgcn_mfma_f32_16x16x32_bf16(af, bw, acc2[f], 0, 0, 0);
            }
        }
    }

    #pragma unroll
    for (int f = 0; f < 8; ++f) {
        int col = f * 16 + lrow;
        float bb = b2[col];
        #pragma unroll
        for (int rr = 0; rr < 4; ++rr) {
            int row = wave * 16 + lk * 4 + rr;
            float xv = ldsxF[row * DD + col];
            out[(long long)(m_base + row) * DD + col] = acc2[f][rr] + bb + xv;
        }
    }
}

extern "C" void kernel_launch(void* const* d_in, const int* in_sizes, int n_in,
                              void* d_out, int out_size, void* d_ws, size_t ws_size,
                              hipStream_t stream) {
    const float* emb = (const float*)d_in[0];
    const int*   knn = (const int*)  d_in[1];
    const float* W1  = (const float*)d_in[2];
    const float* b1  = (const float*)d_in[3];
    const float* W2  = (const float*)d_in[4];
    const float* b2  = (const float*)d_in[5];
    float* out = (float*)d_out;

    unsigned short* Wsw  = (unsigned short*)d_ws;           // 49152 u16 swizzled
    unsigned char*  embq = (unsigned char*)(Wsw + 49152);   // 10,240,000 fp8

    const size_t NEED   = (size_t)98304 + 10240000;         // ~10.3 MB
    const size_t LDSB_F = (size_t)BMF * DD * 4 + (size_t)BMF * MW * 2;

    if (ws_size >= NEED) {
        nr_prep<true><<<5192, 256, 0, stream>>>(emb, W1, W2, embq, Wsw);
        nr_persist<<<512, 256, PT_LDS, stream>>>(
            emb, embq, knn, Wsw, b1, b2, out);
    } else {
        nr_prep<false><<<192, 256, 0, stream>>>(emb, W1, W2, nullptr, Wsw);
        nr_fused_f32<<<8 * NSLOTF, 256, LDSB_F, stream>>>(
            emb, knn, Wsw, b1, b2, out);
    }
}